// Round 1
// baseline (467.644 us; speedup 1.0000x reference)
//
#include <hip/hip_runtime.h>
#include <hip/hip_fp16.h>

#define N_NODES 65536
#define N_EDGES 1048576
#define BUCKET  64   // padded CSR slots per node (deg ~ Poisson(16); P(>64) ~ 1e-18)

typedef float vfloat4 __attribute__((ext_vector_type(4)));
typedef unsigned long long ull;

// ---------------- workspace layout (bytes) ----------------
// counts @ 0x000000   (256 KB)
// dinv   @ 0x040000   (256 KB)
// (rank slot unused)  @ 0x080000
// csr    @ 0x480000   (8 MB, N*64 ushort, zeroed; holes gather row 0, masked)
// xh     @ 0xC80000   (8 MB)  fp16 x (additive Horner term)
// tA     @ 0x1480000  (8 MB)  state t = dinv .* p, fp16
// tB     @ 0x1C80000  (8 MB)

// Fused: count degree and scatter src into padded CSR in one edge pass.
// rank comes straight from the atomicAdd return -> no rank[] round-trip.
__global__ void build_csr(const int* __restrict__ src, const int* __restrict__ dst,
                          int* __restrict__ counts, unsigned short* __restrict__ csr) {
    int e = blockIdx.x * blockDim.x + threadIdx.x;
    if (e >= N_EDGES) return;
    int d = dst[e];
    int r = atomicAdd(&counts[d], 1);
    if (r < BUCKET) csr[d * BUCKET + r] = (unsigned short)src[e];
}

__global__ void compute_dinv(const int* __restrict__ counts, float* __restrict__ dinv) {
    int v = blockIdx.x * blockDim.x + threadIdx.x;
    if (v < N_NODES) dinv[v] = rsqrtf((float)(counts[v] + 1));  // +1 self-loop
}

// t0 = fp16(dinv .* x) (gather state), xh = fp16(x) (additive term)
__global__ void cvt_x(const float* __restrict__ x, const float* __restrict__ dinv,
                      __half* __restrict__ t0, __half* __restrict__ xh) {
    int i = blockIdx.x * blockDim.x + threadIdx.x;  // i < N*16
    int v = i >> 4;
    float dv = dinv[v];
    float4 val = ((const float4*)x)[i];
    __half2 xl = __floats2half2_rn(val.x, val.y);
    __half2 xh2 = __floats2half2_rn(val.z, val.w);
    ull ox = ((ull)(*(const unsigned*)&xh2) << 32) | (*(const unsigned*)&xl);
    __half2 tl = __floats2half2_rn(dv * val.x, dv * val.y);
    __half2 th = __floats2half2_rn(dv * val.z, dv * val.w);
    ull ot = ((ull)(*(const unsigned*)&th) << 32) | (*(const unsigned*)&tl);
    ((ull*)xh)[i] = ox;
    ((ull*)t0)[i] = ot;
}

// Horner hop, dinv folded:  p_out[d] = sc*dinv[d]*(sum_e t[src_e] + t[d]) + temp[k]*x[d]
//                           t_out[d] = dinv[d]*p_out[d]  (k<9; k==9 writes p fp32)
// FOUR nodes per wave (v0..v0+3 wave-uniform -> CSR/meta on the scalar pipe).
// lane = 8q+f: q = edge slot 0..7 per granule, f = feature oct (16 B dwordx4;
// 8 lanes = 128 B row). Granule = 8 slots of one node; per outer step we issue
// TWO granules per node (<=8 gathers / 8 KB in flight per wave). Per-node
// wave-uniform skip (cnt[j] scalar) kills ~45%->~20% of the padded-slot waste.
// ushort CSR: one scalar dwordx4 load covers a granule. Holes gather row 0
// (L1-hot) and are zero-masked.
__global__ void __launch_bounds__(256) hop_kernel(
        const __half* __restrict__ tab, const __half* __restrict__ xh,
        __half* __restrict__ tab_out, float* __restrict__ out_f32,
        const float* __restrict__ temp, const int* __restrict__ counts,
        const unsigned short* __restrict__ csr, const float* __restrict__ dinv,
        int k) {
    int gtid = blockIdx.x * blockDim.x + threadIdx.x;
    int wave = __builtin_amdgcn_readfirstlane(gtid >> 6);
    int lane = gtid & 63;
    int q = lane >> 3;   // edge slot within granule of 8
    int f = lane & 7;    // feature oct (16 B)

    int v0 = wave * 4;
    float tk = temp[k];
    float sc = (k == 1) ? temp[0] : 1.0f;

    int4 cv = *(const int4*)(counts + v0);     // wave-uniform -> s_load_dwordx4
    int cnt[4];
    cnt[0] = min(cv.x, BUCKET); cnt[1] = min(cv.y, BUCKET);
    cnt[2] = min(cv.z, BUCKET); cnt[3] = min(cv.w, BUCKET);
    float4 dvv = *(const float4*)(dinv + v0);
    float dv[4] = {dvv.x, dvv.y, dvv.z, dvv.w};

    int maxc = max(max(cnt[0], cnt[1]), max(cnt[2], cnt[3]));
    int iters = (maxc + 7) >> 3;   // 8-slot granules

    const uint4* t4 = (const uint4*)tab;   // 16 B granule; row = 8 granules = 128 B
    float a[4][8] = {};   // all indices compile-time after unroll -> registers

    for (int r = 0; r < iters; r += 2) {
        #pragma unroll
        for (int j = 0; j < 4; ++j) {
            #pragma unroll
            for (int gg = 0; gg < 2; ++gg) {
                int e0 = (r + gg) * 8;
                if (e0 >= cnt[j]) continue;   // wave-uniform -> s_cbranch skip
                // 8 ushort srcs = 16 B, wave-uniform -> scalar dwordx4 load
                int4 sg = *(const int4*)(csr + (v0 + j) * BUCKET + e0);
                int word = (q & 4) ? ((q & 2) ? sg.w : sg.z)
                                   : ((q & 2) ? sg.y : sg.x);
                int s = (word >> ((q & 1) * 16)) & 0xffff;   // slot e0+q's src
                uint4 row = t4[s * 8 + f];
                bool valid = (e0 + q) < cnt[j];              // mask tail holes
                unsigned rx = valid ? row.x : 0u;
                unsigned ry = valid ? row.y : 0u;
                unsigned rz = valid ? row.z : 0u;
                unsigned rw = valid ? row.w : 0u;
                float2 p0 = __half22float2(*(const __half2*)&rx);
                float2 p1 = __half22float2(*(const __half2*)&ry);
                float2 p2 = __half22float2(*(const __half2*)&rz);
                float2 p3 = __half22float2(*(const __half2*)&rw);
                a[j][0] += p0.x; a[j][1] += p0.y;
                a[j][2] += p1.x; a[j][3] += p1.y;
                a[j][4] += p2.x; a[j][5] += p2.y;
                a[j][6] += p3.x; a[j][7] += p3.y;
            }
        }
    }

    // reduce across the 8 slot-lanes (bits 3,4,5 of lane)
    #pragma unroll
    for (int j = 0; j < 4; ++j) {
        #pragma unroll
        for (int t = 0; t < 8; ++t) {
            a[j][t] += __shfl_xor(a[j][t], 8);
            a[j][t] += __shfl_xor(a[j][t], 16);
            a[j][t] += __shfl_xor(a[j][t], 32);
        }
    }

    #pragma unroll
    for (int j = 0; j < 4; ++j) {
        int v = v0 + j;
        uint4 sx = ((const uint4*)xh)[v * 8 + f];   // additive x term (fp16)
        uint4 st = t4[v * 8 + f];                   // self term t[d]
        float2 x0 = __half22float2(*(const __half2*)&sx.x);
        float2 x1 = __half22float2(*(const __half2*)&sx.y);
        float2 x2 = __half22float2(*(const __half2*)&sx.z);
        float2 x3 = __half22float2(*(const __half2*)&sx.w);
        float2 s0 = __half22float2(*(const __half2*)&st.x);
        float2 s1 = __half22float2(*(const __half2*)&st.y);
        float2 s2 = __half22float2(*(const __half2*)&st.z);
        float2 s3 = __half22float2(*(const __half2*)&st.w);
        float m = sc * dv[j];
        float r0 = m * (a[j][0] + s0.x) + tk * x0.x;
        float r1 = m * (a[j][1] + s0.y) + tk * x0.y;
        float r2 = m * (a[j][2] + s1.x) + tk * x1.x;
        float r3 = m * (a[j][3] + s1.y) + tk * x1.y;
        float r4 = m * (a[j][4] + s2.x) + tk * x2.x;
        float r5 = m * (a[j][5] + s2.y) + tk * x2.y;
        float r6 = m * (a[j][6] + s3.x) + tk * x3.x;
        float r7 = m * (a[j][7] + s3.y) + tk * x3.y;
        if (q == 0) {   // lanes 0..7 -> contiguous 128 B (fp16) / 256 B (fp32)
            if (k == 9) {
                vfloat4 o0 = {r0, r1, r2, r3};
                vfloat4 o1 = {r4, r5, r6, r7};
                ((vfloat4*)out_f32)[v * 16 + 2 * f]     = o0;
                ((vfloat4*)out_f32)[v * 16 + 2 * f + 1] = o1;
            } else {
                float d2 = dv[j];
                __half2 h0 = __floats2half2_rn(d2 * r0, d2 * r1);
                __half2 h1 = __floats2half2_rn(d2 * r2, d2 * r3);
                __half2 h2 = __floats2half2_rn(d2 * r4, d2 * r5);
                __half2 h3 = __floats2half2_rn(d2 * r6, d2 * r7);
                uint4 o;
                o.x = *(const unsigned*)&h0;
                o.y = *(const unsigned*)&h1;
                o.z = *(const unsigned*)&h2;
                o.w = *(const unsigned*)&h3;
                ((uint4*)tab_out)[v * 8 + f] = o;
            }
        }
    }
}

extern "C" void kernel_launch(void* const* d_in, const int* in_sizes, int n_in,
                              void* d_out, int out_size, void* d_ws, size_t ws_size,
                              hipStream_t stream) {
    const float* x    = (const float*)d_in[0];
    const float* temp = (const float*)d_in[1];
    const int*   ei   = (const int*)d_in[2];
    const int* src = ei;             // edge_index[0]
    const int* dst = ei + N_EDGES;   // edge_index[1]
    float* out = (float*)d_out;

    char* ws = (char*)d_ws;
    int*            counts = (int*)            (ws + 0x000000);
    float*          dinv   = (float*)          (ws + 0x040000);
    unsigned short* csr    = (unsigned short*) (ws + 0x480000);   // 8 MB
    __half*         xh     = (__half*)         (ws + 0xC80000);
    __half*         tA     = (__half*)         (ws + 0x1480000);
    __half*         tB     = (__half*)         (ws + 0x1C80000);

    (void)hipMemsetAsync(counts, 0, N_NODES * sizeof(int), stream);
    (void)hipMemsetAsync(csr, 0, N_NODES * BUCKET * sizeof(unsigned short), stream);

    build_csr<<<N_EDGES / 256, 256, 0, stream>>>(src, dst, counts, csr);
    compute_dinv<<<N_NODES / 256, 256, 0, stream>>>(counts, dinv);
    cvt_x<<<(N_NODES * 16) / 256, 256, 0, stream>>>(x, dinv, tA, xh);

    // Horner: p = temp[0]*x; for k=1..9: p = A_hat*p + temp[k]*x (scale fused in hop1)
    // Table invariant t_k = dinv .* p_k; ping-pong tA -> tB -> tA ...
    const int hop_blocks = (N_NODES / 4) * 64 / 256;  // 4 nodes per wave
    const __half* gin = tA;
    for (int k = 1; k <= 9; ++k) {
        __half* gout = (k & 1) ? tB : tA;
        hop_kernel<<<hop_blocks, 256, 0, stream>>>(gin, xh, gout, out, temp,
                                                   counts, csr, dinv, k);
        gin = gout;
    }
}

// Round 2
// 427.901 us; speedup vs baseline: 1.0929x; 1.0929x over previous
//
#include <hip/hip_runtime.h>
#include <hip/hip_fp16.h>

#define N_NODES 65536
#define N_EDGES 1048576
#define BUCKET  64   // padded CSR slots per node (deg ~ Poisson(16); P(>64) ~ 1e-18)

typedef float vfloat4 __attribute__((ext_vector_type(4)));
typedef unsigned long long ull;

// ---------------- workspace layout (bytes) ----------------
// counts @ 0x000000   (256 KB)
// dinv   @ 0x040000   (256 KB)
// csr    @ 0x480000   (8 MB, N*64 ushort, zeroed; holes gather row 0, masked)
// xh     @ 0xC80000   (8 MB)  fp16 x (additive Horner term)
// tA     @ 0x1480000  (8 MB)  state t = dinv .* p, fp16
// tB     @ 0x1C80000  (8 MB)

// Fused CSR build, FOUR edges per thread: the kernel is latency-bound on the
// atomicAdd return (VALUBusy 0.4%, HBM 10%), so batch 4 independent atomics
// in flight per thread to amortize the L2/LLC round trip.
__global__ void build_csr(const int* __restrict__ src, const int* __restrict__ dst,
                          int* __restrict__ counts, unsigned short* __restrict__ csr) {
    int t = blockIdx.x * blockDim.x + threadIdx.x;
    int e = t * 4;
    if (e >= N_EDGES) return;
    int4 d4 = *(const int4*)(dst + e);
    int4 s4 = *(const int4*)(src + e);
    int r0 = atomicAdd(&counts[d4.x], 1);   // 4 independent round trips overlap
    int r1 = atomicAdd(&counts[d4.y], 1);
    int r2 = atomicAdd(&counts[d4.z], 1);
    int r3 = atomicAdd(&counts[d4.w], 1);
    if (r0 < BUCKET) csr[d4.x * BUCKET + r0] = (unsigned short)s4.x;
    if (r1 < BUCKET) csr[d4.y * BUCKET + r1] = (unsigned short)s4.y;
    if (r2 < BUCKET) csr[d4.z * BUCKET + r2] = (unsigned short)s4.z;
    if (r3 < BUCKET) csr[d4.w * BUCKET + r3] = (unsigned short)s4.w;
}

__global__ void compute_dinv(const int* __restrict__ counts, float* __restrict__ dinv) {
    int v = blockIdx.x * blockDim.x + threadIdx.x;
    if (v < N_NODES) dinv[v] = rsqrtf((float)(counts[v] + 1));  // +1 self-loop
}

// t0 = fp16(dinv .* x) (gather state), xh = fp16(x) (additive term)
__global__ void cvt_x(const float* __restrict__ x, const float* __restrict__ dinv,
                      __half* __restrict__ t0, __half* __restrict__ xh) {
    int i = blockIdx.x * blockDim.x + threadIdx.x;  // i < N*16
    int v = i >> 4;
    float dv = dinv[v];
    float4 val = ((const float4*)x)[i];
    __half2 xl = __floats2half2_rn(val.x, val.y);
    __half2 xh2 = __floats2half2_rn(val.z, val.w);
    ull ox = ((ull)(*(const unsigned*)&xh2) << 32) | (*(const unsigned*)&xl);
    __half2 tl = __floats2half2_rn(dv * val.x, dv * val.y);
    __half2 th = __floats2half2_rn(dv * val.z, dv * val.w);
    ull ot = ((ull)(*(const unsigned*)&th) << 32) | (*(const unsigned*)&tl);
    ((ull*)xh)[i] = ox;
    ((ull*)t0)[i] = ot;
}

// Horner hop, dinv folded:  p_out[d] = sc*dinv[d]*(sum_e t[src_e] + t[d]) + temp[k]*x[d]
//                           t_out[d] = dinv[d]*p_out[d]  (k<9; k==9 writes p fp32)
// FOUR nodes per wave (v0..v0+3 wave-uniform -> CSR/meta on the scalar pipe).
// lane = 8q+f: q = edge slot 0..7 per granule, f = feature oct (16 B dwordx4;
// 8 lanes = 128 B row). 16 slots per node per iter via 2 granules; all 8 row
// gathers of an iteration are issued branch-free (round-0 structure) so the
// compiler batches them before the first waitcnt — MLP over work-skipping
// (round-1's per-node skip branches cost +11 µs/hop). ushort CSR: two scalar
// dwordx4 loads cover 16 slots. Holes gather row 0 (L1-hot), zero-masked.
__global__ void __launch_bounds__(256) hop_kernel(
        const __half* __restrict__ tab, const __half* __restrict__ xh,
        __half* __restrict__ tab_out, float* __restrict__ out_f32,
        const float* __restrict__ temp, const int* __restrict__ counts,
        const unsigned short* __restrict__ csr, const float* __restrict__ dinv,
        int k) {
    int gtid = blockIdx.x * blockDim.x + threadIdx.x;
    int wave = __builtin_amdgcn_readfirstlane(gtid >> 6);
    int lane = gtid & 63;
    int q = lane >> 3;   // edge slot within granule of 8
    int f = lane & 7;    // feature oct (16 B)

    int v0 = wave * 4;
    float tk = temp[k];
    float sc = (k == 1) ? temp[0] : 1.0f;

    int4 cv = *(const int4*)(counts + v0);     // wave-uniform -> s_load_dwordx4
    int cnt[4];
    cnt[0] = min(cv.x, BUCKET); cnt[1] = min(cv.y, BUCKET);
    cnt[2] = min(cv.z, BUCKET); cnt[3] = min(cv.w, BUCKET);
    float4 dvv = *(const float4*)(dinv + v0);
    float dv[4] = {dvv.x, dvv.y, dvv.z, dvv.w};

    int maxc = max(max(cnt[0], cnt[1]), max(cnt[2], cnt[3]));
    int iters = (maxc + 15) >> 4;   // 16 slots per node per iteration

    const uint4* t4 = (const uint4*)tab;   // 16 B granule; row = 8 granules = 128 B
    float a[4][8] = {};   // compile-time indices after unroll -> registers

    for (int r = 0; r < iters; ++r) {
        int e0 = r * 16;
        #pragma unroll
        for (int j = 0; j < 4; ++j) {
            // 16 ushort srcs = 32 B, wave-uniform -> two scalar dwordx4 loads
            const int4* bp = (const int4*)(csr + (v0 + j) * BUCKET + e0);
            int4 sgA = bp[0];   // slots 0..7
            int4 sgB = bp[1];   // slots 8..15
            #pragma unroll
            for (int g = 0; g < 2; ++g) {
                int4 sg = g ? sgB : sgA;
                int word = (q & 4) ? ((q & 2) ? sg.w : sg.z)
                                   : ((q & 2) ? sg.y : sg.x);
                int s = (word >> ((q & 1) * 16)) & 0xffff;  // slot e0+8g+q's src
                uint4 row = t4[s * 8 + f];
                bool valid = (e0 + 8 * g + q) < cnt[j];     // mask padded holes
                unsigned rx = valid ? row.x : 0u;
                unsigned ry = valid ? row.y : 0u;
                unsigned rz = valid ? row.z : 0u;
                unsigned rw = valid ? row.w : 0u;
                float2 p0 = __half22float2(*(const __half2*)&rx);
                float2 p1 = __half22float2(*(const __half2*)&ry);
                float2 p2 = __half22float2(*(const __half2*)&rz);
                float2 p3 = __half22float2(*(const __half2*)&rw);
                a[j][0] += p0.x; a[j][1] += p0.y;
                a[j][2] += p1.x; a[j][3] += p1.y;
                a[j][4] += p2.x; a[j][5] += p2.y;
                a[j][6] += p3.x; a[j][7] += p3.y;
            }
        }
    }

    // reduce across the 8 slot-lanes (lane bits 3,4,5)
    #pragma unroll
    for (int j = 0; j < 4; ++j) {
        #pragma unroll
        for (int t = 0; t < 8; ++t) {
            a[j][t] += __shfl_xor(a[j][t], 8);
            a[j][t] += __shfl_xor(a[j][t], 16);
            a[j][t] += __shfl_xor(a[j][t], 32);
        }
    }

    #pragma unroll
    for (int j = 0; j < 4; ++j) {
        int v = v0 + j;
        uint4 sx = ((const uint4*)xh)[v * 8 + f];   // additive x term (fp16)
        uint4 st = t4[v * 8 + f];                   // self term t[d]
        float2 x0 = __half22float2(*(const __half2*)&sx.x);
        float2 x1 = __half22float2(*(const __half2*)&sx.y);
        float2 x2 = __half22float2(*(const __half2*)&sx.z);
        float2 x3 = __half22float2(*(const __half2*)&sx.w);
        float2 s0 = __half22float2(*(const __half2*)&st.x);
        float2 s1 = __half22float2(*(const __half2*)&st.y);
        float2 s2 = __half22float2(*(const __half2*)&st.z);
        float2 s3 = __half22float2(*(const __half2*)&st.w);
        float m = sc * dv[j];
        float r0 = m * (a[j][0] + s0.x) + tk * x0.x;
        float r1 = m * (a[j][1] + s0.y) + tk * x0.y;
        float r2 = m * (a[j][2] + s1.x) + tk * x1.x;
        float r3 = m * (a[j][3] + s1.y) + tk * x1.y;
        float r4 = m * (a[j][4] + s2.x) + tk * x2.x;
        float r5 = m * (a[j][5] + s2.y) + tk * x2.y;
        float r6 = m * (a[j][6] + s3.x) + tk * x3.x;
        float r7 = m * (a[j][7] + s3.y) + tk * x3.y;
        if (q == 0) {   // lanes 0..7 -> contiguous 128 B (fp16) / 256 B (fp32)
            if (k == 9) {
                vfloat4 o0 = {r0, r1, r2, r3};
                vfloat4 o1 = {r4, r5, r6, r7};
                ((vfloat4*)out_f32)[v * 16 + 2 * f]     = o0;
                ((vfloat4*)out_f32)[v * 16 + 2 * f + 1] = o1;
            } else {
                float d2 = dv[j];
                __half2 h0 = __floats2half2_rn(d2 * r0, d2 * r1);
                __half2 h1 = __floats2half2_rn(d2 * r2, d2 * r3);
                __half2 h2 = __floats2half2_rn(d2 * r4, d2 * r5);
                __half2 h3 = __floats2half2_rn(d2 * r6, d2 * r7);
                uint4 o;
                o.x = *(const unsigned*)&h0;
                o.y = *(const unsigned*)&h1;
                o.z = *(const unsigned*)&h2;
                o.w = *(const unsigned*)&h3;
                ((uint4*)tab_out)[v * 8 + f] = o;
            }
        }
    }
}

extern "C" void kernel_launch(void* const* d_in, const int* in_sizes, int n_in,
                              void* d_out, int out_size, void* d_ws, size_t ws_size,
                              hipStream_t stream) {
    const float* x    = (const float*)d_in[0];
    const float* temp = (const float*)d_in[1];
    const int*   ei   = (const int*)d_in[2];
    const int* src = ei;             // edge_index[0]
    const int* dst = ei + N_EDGES;   // edge_index[1]
    float* out = (float*)d_out;

    char* ws = (char*)d_ws;
    int*            counts = (int*)            (ws + 0x000000);
    float*          dinv   = (float*)          (ws + 0x040000);
    unsigned short* csr    = (unsigned short*) (ws + 0x480000);   // 8 MB
    __half*         xh     = (__half*)         (ws + 0xC80000);
    __half*         tA     = (__half*)         (ws + 0x1480000);
    __half*         tB     = (__half*)         (ws + 0x1C80000);

    (void)hipMemsetAsync(counts, 0, N_NODES * sizeof(int), stream);
    (void)hipMemsetAsync(csr, 0, N_NODES * BUCKET * sizeof(unsigned short), stream);

    build_csr<<<N_EDGES / (256 * 4), 256, 0, stream>>>(src, dst, counts, csr);
    compute_dinv<<<N_NODES / 256, 256, 0, stream>>>(counts, dinv);
    cvt_x<<<(N_NODES * 16) / 256, 256, 0, stream>>>(x, dinv, tA, xh);

    // Horner: p = temp[0]*x; for k=1..9: p = A_hat*p + temp[k]*x (scale fused in hop1)
    // Table invariant t_k = dinv .* p_k; ping-pong tA -> tB -> tA ...
    const int hop_blocks = (N_NODES / 4) * 64 / 256;  // 4 nodes per wave
    const __half* gin = tA;
    for (int k = 1; k <= 9; ++k) {
        __half* gout = (k & 1) ? tB : tA;
        hop_kernel<<<hop_blocks, 256, 0, stream>>>(gin, xh, gout, out, temp,
                                                   counts, csr, dinv, k);
        gin = gout;
    }
}

// Round 3
// 404.259 us; speedup vs baseline: 1.1568x; 1.0585x over previous
//
#include <hip/hip_runtime.h>
#include <hip/hip_fp16.h>

#define N_NODES 65536
#define N_EDGES 1048576
#define BUCKET  64   // padded CSR slots per node (deg ~ Poisson(16); P(>64) ~ 1e-18)

typedef float vfloat4 __attribute__((ext_vector_type(4)));
typedef unsigned long long ull;

// ---------------- workspace layout (bytes) ----------------
// counts @ 0x000000   (256 KB)
// dinv   @ 0x040000   (256 KB)
// rank   @ 0x080000   (4 MB)
// csr    @ 0x480000   (8 MB, N*64 ushort, zeroed; holes gather row 0, masked)
// xh     @ 0xC80000   (8 MB)  fp16 x (additive Horner term)
// tA     @ 0x1480000  (8 MB)  state t = dinv .* p, fp16
// tB     @ 0x1C80000  (8 MB)  -- total 36.5 MB

// Round-0 split build (measured faster than the fused single-pass variant):
// count assigns rank via atomic return; scatter re-reads rank and places src.
__global__ void count_deg(const int* __restrict__ dst, int* __restrict__ counts,
                          int* __restrict__ rank) {
    int e = blockIdx.x * blockDim.x + threadIdx.x;
    if (e < N_EDGES) rank[e] = atomicAdd(&counts[dst[e]], 1);
}

__global__ void compute_dinv(const int* __restrict__ counts, float* __restrict__ dinv) {
    int v = blockIdx.x * blockDim.x + threadIdx.x;
    if (v < N_NODES) dinv[v] = rsqrtf((float)(counts[v] + 1));  // +1 self-loop
}

__global__ void scatter_src(const int* __restrict__ src, const int* __restrict__ dst,
                            const int* __restrict__ rank,
                            unsigned short* __restrict__ csr) {
    int e = blockIdx.x * blockDim.x + threadIdx.x;
    if (e >= N_EDGES) return;
    int r = rank[e];
    if (r < BUCKET) csr[dst[e] * BUCKET + r] = (unsigned short)src[e];
}

// t0 = fp16(dinv .* x) (gather state), xh = fp16(x) (additive term)
// x / xh are pure streams -> non-temporal; t0 (tA) is hop-1's gather table -> normal.
__global__ void cvt_x(const float* __restrict__ x, const float* __restrict__ dinv,
                      __half* __restrict__ t0, __half* __restrict__ xh) {
    int i = blockIdx.x * blockDim.x + threadIdx.x;  // i < N*16
    int v = i >> 4;
    float dv = dinv[v];
    vfloat4 val = __builtin_nontemporal_load((const vfloat4*)x + i);
    __half2 xl = __floats2half2_rn(val.x, val.y);
    __half2 xh2 = __floats2half2_rn(val.z, val.w);
    ull ox = ((ull)(*(const unsigned*)&xh2) << 32) | (*(const unsigned*)&xl);
    __half2 tl = __floats2half2_rn(dv * val.x, dv * val.y);
    __half2 th = __floats2half2_rn(dv * val.z, dv * val.w);
    ull ot = ((ull)(*(const unsigned*)&th) << 32) | (*(const unsigned*)&tl);
    __builtin_nontemporal_store(ox, (ull*)xh + i);
    ((ull*)t0)[i] = ot;
}

// Horner hop, dinv folded:  p_out[d] = sc*dinv[d]*(sum_e t[src_e] + t[d]) + temp[k]*x[d]
//                           t_out[d] = dinv[d]*p_out[d]  (k<9; k==9 writes p fp32)
// FOUR nodes per wave (v0..v0+3 wave-uniform -> CSR/meta on the scalar pipe).
// lane = 16q+f: q = edge slot 0..3 per granule-of-4, f = feature quad (8 B;
// 16 lanes = 128 B row). 32 slots per node per block via 8 granules -> 32
// independent row-gathers in flight per wave (2x round-0's 16; the hop is
// latency*concurrency-bound, per-wave MLP is the binding variable: 16 > 8 > 2
// in-flight ranked exactly with measured hop speed across rounds 0-2).
// iters = ceil(maxc/32) = 1 for >99.9% of waves (P(deg>32) ~ 1e-4).
// ushort CSR: four scalar dwordx4 loads cover 32 slots. Holes gather row 0
// (L1-hot) and are zero-masked. xh is a pure stream -> non-temporal, keeping
// the 8 MB gather table hotter in each XCD's 4 MB L2.
__global__ void __launch_bounds__(256) hop_kernel(
        const __half* __restrict__ tab, const __half* __restrict__ xh,
        __half* __restrict__ tab_out, float* __restrict__ out_f32,
        const float* __restrict__ temp, const int* __restrict__ counts,
        const unsigned short* __restrict__ csr, const float* __restrict__ dinv,
        int k) {
    int gtid = blockIdx.x * blockDim.x + threadIdx.x;
    int wave = __builtin_amdgcn_readfirstlane(gtid >> 6);
    int lane = gtid & 63;
    int q = lane >> 4;   // edge slot within granule of 4
    int f = lane & 15;   // feature quad (8 B)

    int v0 = wave * 4;
    float tk = temp[k];
    float sc = (k == 1) ? temp[0] : 1.0f;

    int4 cv = *(const int4*)(counts + v0);     // wave-uniform -> s_load_dwordx4
    int cnt[4];
    cnt[0] = min(cv.x, BUCKET); cnt[1] = min(cv.y, BUCKET);
    cnt[2] = min(cv.z, BUCKET); cnt[3] = min(cv.w, BUCKET);
    float4 dvv = *(const float4*)(dinv + v0);
    float dv[4] = {dvv.x, dvv.y, dvv.z, dvv.w};

    int maxc = max(max(cnt[0], cnt[1]), max(cnt[2], cnt[3]));
    int iters = (maxc + 31) >> 5;   // 32 slots per node per iteration (~always 1)

    const ull* t2 = (const ull*)tab;   // 8 B granule; row = 16 granules = 128 B
    float a0[4] = {0.f, 0.f, 0.f, 0.f};
    float a1[4] = {0.f, 0.f, 0.f, 0.f};
    float a2[4] = {0.f, 0.f, 0.f, 0.f};
    float a3[4] = {0.f, 0.f, 0.f, 0.f};

    for (int r = 0; r < iters; ++r) {
        int e0 = r * 32;
        #pragma unroll
        for (int j = 0; j < 4; ++j) {
            // 32 ushort srcs = 64 B, wave-uniform -> scalar dwordx4 loads
            const int4* bp = (const int4*)(csr + (v0 + j) * BUCKET + e0);
            int4 sg0 = bp[0];   // slots  0..7
            int4 sg1 = bp[1];   // slots  8..15
            int4 sg2 = bp[2];   // slots 16..23
            int4 sg3 = bp[3];   // slots 24..31
            #pragma unroll
            for (int g = 0; g < 8; ++g) {
                int4 sg = (g < 2) ? sg0 : (g < 4) ? sg1 : (g < 6) ? sg2 : sg3;
                int word = (g & 1) ? ((q & 2) ? sg.w : sg.z)
                                   : ((q & 2) ? sg.y : sg.x);
                int s = (word >> ((q & 1) * 16)) & 0xffff;   // slot e0+4g+q's src
                ull row = t2[s * 16 + f];
                row = ((e0 + 4 * g + q) < cnt[j]) ? row : 0ull;  // mask holes
                unsigned rl = (unsigned)row, rh = (unsigned)(row >> 32);
                float2 lo = __half22float2(*(const __half2*)&rl);
                float2 hi = __half22float2(*(const __half2*)&rh);
                a0[j] += lo.x; a1[j] += lo.y; a2[j] += hi.x; a3[j] += hi.y;
            }
        }
    }

    #pragma unroll
    for (int j = 0; j < 4; ++j) {
        a0[j] += __shfl_xor(a0[j], 16); a0[j] += __shfl_xor(a0[j], 32);
        a1[j] += __shfl_xor(a1[j], 16); a1[j] += __shfl_xor(a1[j], 32);
        a2[j] += __shfl_xor(a2[j], 16); a2[j] += __shfl_xor(a2[j], 32);
        a3[j] += __shfl_xor(a3[j], 16); a3[j] += __shfl_xor(a3[j], 32);
    }

    #pragma unroll
    for (int j = 0; j < 4; ++j) {
        int v = v0 + j;
        ull sx = __builtin_nontemporal_load((const ull*)xh + v * 16 + f);
        ull st = t2[v * 16 + f];                 // self term t[d] (table, L2-warm)
        unsigned sxl = (unsigned)sx, sxh2 = (unsigned)(sx >> 32);
        unsigned stl = (unsigned)st, sth = (unsigned)(st >> 32);
        float2 xlo = __half22float2(*(const __half2*)&sxl);
        float2 xhi = __half22float2(*(const __half2*)&sxh2);
        float2 slo = __half22float2(*(const __half2*)&stl);
        float2 shi = __half22float2(*(const __half2*)&sth);
        float m = sc * dv[j];
        float r0 = m * (a0[j] + slo.x) + tk * xlo.x;
        float r1 = m * (a1[j] + slo.y) + tk * xlo.y;
        float r2 = m * (a2[j] + shi.x) + tk * xhi.x;
        float r3 = m * (a3[j] + shi.y) + tk * xhi.y;
        if (q == 0) {
            if (k == 9) {
                vfloat4 o = {r0, r1, r2, r3};
                __builtin_nontemporal_store(o, (vfloat4*)out_f32 + v * 16 + f);
            } else {
                float d2 = dv[j];
                __half2 plo = __floats2half2_rn(d2 * r0, d2 * r1);
                __half2 phi = __floats2half2_rn(d2 * r2, d2 * r3);
                ull o = ((ull)(*(const unsigned*)&phi) << 32)
                      | (*(const unsigned*)&plo);
                ((ull*)tab_out)[v * 16 + f] = o;   // next hop's table -> keep in L2
            }
        }
    }
}

extern "C" void kernel_launch(void* const* d_in, const int* in_sizes, int n_in,
                              void* d_out, int out_size, void* d_ws, size_t ws_size,
                              hipStream_t stream) {
    const float* x    = (const float*)d_in[0];
    const float* temp = (const float*)d_in[1];
    const int*   ei   = (const int*)d_in[2];
    const int* src = ei;             // edge_index[0]
    const int* dst = ei + N_EDGES;   // edge_index[1]
    float* out = (float*)d_out;

    char* ws = (char*)d_ws;
    int*            counts = (int*)            (ws + 0x000000);
    float*          dinv   = (float*)          (ws + 0x040000);
    int*            rank   = (int*)            (ws + 0x080000);
    unsigned short* csr    = (unsigned short*) (ws + 0x480000);   // 8 MB
    __half*         xh     = (__half*)         (ws + 0xC80000);
    __half*         tA     = (__half*)         (ws + 0x1480000);
    __half*         tB     = (__half*)         (ws + 0x1C80000);

    (void)hipMemsetAsync(counts, 0, N_NODES * sizeof(int), stream);
    (void)hipMemsetAsync(csr, 0, N_NODES * BUCKET * sizeof(unsigned short), stream);

    count_deg<<<N_EDGES / 256, 256, 0, stream>>>(dst, counts, rank);
    compute_dinv<<<N_NODES / 256, 256, 0, stream>>>(counts, dinv);
    scatter_src<<<N_EDGES / 256, 256, 0, stream>>>(src, dst, rank, csr);
    cvt_x<<<(N_NODES * 16) / 256, 256, 0, stream>>>(x, dinv, tA, xh);

    // Horner: p = temp[0]*x; for k=1..9: p = A_hat*p + temp[k]*x (scale fused in hop1)
    // Table invariant t_k = dinv .* p_k; ping-pong tA -> tB -> tA ...
    const int hop_blocks = (N_NODES / 4) * 64 / 256;  // 4 nodes per wave
    const __half* gin = tA;
    for (int k = 1; k <= 9; ++k) {
        __half* gout = (k & 1) ? tB : tA;
        hop_kernel<<<hop_blocks, 256, 0, stream>>>(gin, xh, gout, out, temp,
                                                   counts, csr, dinv, k);
        gin = gout;
    }
}

// Round 4
// 378.941 us; speedup vs baseline: 1.2341x; 1.0668x over previous
//
#include <hip/hip_runtime.h>
#include <hip/hip_fp16.h>

#define N_NODES 65536
#define N_EDGES 1048576
#define BUCKET  64    // 2 half-buckets x 32 slots per node
#define HBKT    32    // per-half slots (deg/half ~ Poisson(8); P(>32) ~ 1e-11)

typedef float vfloat4 __attribute__((ext_vector_type(4)));
typedef unsigned long long ull;

// ---------------- workspace layout (bytes) ----------------
// counts @ 0x000000   (512 KB: counts[half*N + v], in-degree per src-half)
// rank   @ 0x080000   (4 MB)  -- dead after scatter_src
// dinv   @ 0x080000   (256 KB; ALIASES rank head, written after scatter_src)
// csr    @ 0x480000   (8 MB, N*64 ushort: [node][half][slot]; zeroed)
// xh     @ 0xC80000   (8 MB)  fp16 x (additive Horner term)
// tA     @ 0x1480000  (8 MB)  state t = dinv .* p, fp16
// tB     @ 0x1C80000  (8 MB)  -- end 0x2480000, identical footprint to round 0

// Rank within (dst, src-half) bucket via atomic return.
__global__ void count_deg(const int* __restrict__ src, const int* __restrict__ dst,
                          int* __restrict__ counts, int* __restrict__ rank) {
    int e = blockIdx.x * blockDim.x + threadIdx.x;
    if (e >= N_EDGES) return;
    int h = src[e] >> 15;   // partition by SOURCE half = gather-address half
    rank[e] = atomicAdd(&counts[h * N_NODES + dst[e]], 1);
}

__global__ void scatter_src(const int* __restrict__ src, const int* __restrict__ dst,
                            const int* __restrict__ rank,
                            unsigned short* __restrict__ csr) {
    int e = blockIdx.x * blockDim.x + threadIdx.x;
    if (e >= N_EDGES) return;
    int r = rank[e];
    int s = src[e];
    int h = s >> 15;
    if (r < HBKT) csr[dst[e] * BUCKET + h * HBKT + r] = (unsigned short)s;
}

// runs AFTER scatter_src (dinv aliases the dead rank buffer)
__global__ void compute_dinv(const int* __restrict__ counts, float* __restrict__ dinv) {
    int v = blockIdx.x * blockDim.x + threadIdx.x;
    if (v >= N_NODES) return;
    int deg = counts[v] + counts[N_NODES + v];
    dinv[v] = rsqrtf((float)(deg + 1));   // +1 self-loop
}

// t0 = fp16(dinv .* x) (gather state), xh = fp16(x) (additive term)
__global__ void cvt_x(const float* __restrict__ x, const float* __restrict__ dinv,
                      __half* __restrict__ t0, __half* __restrict__ xh) {
    int i = blockIdx.x * blockDim.x + threadIdx.x;  // i < N*16
    int v = i >> 4;
    float dv = dinv[v];
    float4 val = ((const float4*)x)[i];
    __half2 xl = __floats2half2_rn(val.x, val.y);
    __half2 xh2 = __floats2half2_rn(val.z, val.w);
    ull ox = ((ull)(*(const unsigned*)&xh2) << 32) | (*(const unsigned*)&xl);
    __half2 tl = __floats2half2_rn(dv * val.x, dv * val.y);
    __half2 th = __floats2half2_rn(dv * val.z, dv * val.w);
    ull ot = ((ull)(*(const unsigned*)&th) << 32) | (*(const unsigned*)&tl);
    ((ull*)xh)[i] = ox;
    ((ull*)t0)[i] = ot;
}

// Horner hop, dinv folded:  p_out[d] = sc*dinv[d]*(sum_e t[src_e] + t[d]) + temp[k]*x[d]
//                           t_out[d] = dinv[d]*p_out[d]  (k<9; k==9 writes p fp32)
// FOUR nodes per wave; lane = 16q+f (q = slot-in-granule-of-4, f = feature quad,
// 8 B; 16 lanes = one 128 B row). Round-0's proven pipeline shape: 16
// independent row-gathers per dependence-free block, sequential iterations.
// NEW: the CSR bucket is split by src-half, and the hop gathers in TWO
// sequential phases (low half 0..32767, then high). Each phase's address
// range is a 4 MB sub-table that fits a per-XCD L2 -> ~all-L2-hit gathers
// instead of a 50/50 L2/LLC mix (the table is 8 MB vs 4 MB L2/XCD).
// sched_barrier(0) between phases keeps the compiler from fusing them into
// one 32-wide block (round-3's shape: VGPR pressure, measured -4.7 us/hop).
__global__ void __launch_bounds__(256) hop_kernel(
        const __half* __restrict__ tab, const __half* __restrict__ xh,
        __half* __restrict__ tab_out, float* __restrict__ out_f32,
        const float* __restrict__ temp, const int* __restrict__ counts,
        const unsigned short* __restrict__ csr, const float* __restrict__ dinv,
        int k) {
    int gtid = blockIdx.x * blockDim.x + threadIdx.x;
    int wave = __builtin_amdgcn_readfirstlane(gtid >> 6);
    int lane = gtid & 63;
    int q = lane >> 4;   // edge slot within granule of 4
    int f = lane & 15;   // feature quad (8 B)

    int v0 = wave * 4;
    float tk = temp[k];
    float sc = (k == 1) ? temp[0] : 1.0f;

    int4 cvL = *(const int4*)(counts + v0);             // low-half in-degrees
    int4 cvH = *(const int4*)(counts + N_NODES + v0);   // high-half in-degrees
    int cl[4] = {min(cvL.x, HBKT), min(cvL.y, HBKT), min(cvL.z, HBKT), min(cvL.w, HBKT)};
    int ch[4] = {min(cvH.x, HBKT), min(cvH.y, HBKT), min(cvH.z, HBKT), min(cvH.w, HBKT)};
    float4 dvv = *(const float4*)(dinv + v0);
    float dv[4] = {dvv.x, dvv.y, dvv.z, dvv.w};

    const ull* t2 = (const ull*)tab;   // 8 B granule; row = 16 granules = 128 B
    float a0[4] = {0.f, 0.f, 0.f, 0.f};
    float a1[4] = {0.f, 0.f, 0.f, 0.f};
    float a2[4] = {0.f, 0.f, 0.f, 0.f};
    float a3[4] = {0.f, 0.f, 0.f, 0.f};

    // one phase: scan [off, off+HBKT) slots masked by per-node count cn[]
    auto phase = [&](int off, const int (&cn)[4]) {
        int maxc = max(max(cn[0], cn[1]), max(cn[2], cn[3]));
        int iters = (maxc + 15) >> 4;   // 16 slots per node per iteration
        for (int r = 0; r < iters; ++r) {
            int e0 = r * 16;
            #pragma unroll
            for (int j = 0; j < 4; ++j) {
                // 16 ushort srcs = 32 B, wave-uniform -> two scalar dwordx4 loads
                const int4* bp = (const int4*)(csr + (v0 + j) * BUCKET + off + e0);
                int4 sgA = bp[0];   // slots 0..7 of this block
                int4 sgB = bp[1];   // slots 8..15
                #pragma unroll
                for (int g = 0; g < 4; ++g) {
                    int4 sg = (g & 2) ? sgB : sgA;
                    int word = (g & 1) ? ((q & 2) ? sg.w : sg.z)
                                       : ((q & 2) ? sg.y : sg.x);
                    int s = (word >> ((q & 1) * 16)) & 0xffff;  // slot e0+4g+q's src
                    ull row = t2[s * 16 + f];
                    row = ((e0 + 4 * g + q) < cn[j]) ? row : 0ull;  // mask holes
                    unsigned rl = (unsigned)row, rh = (unsigned)(row >> 32);
                    float2 lo = __half22float2(*(const __half2*)&rl);
                    float2 hi = __half22float2(*(const __half2*)&rh);
                    a0[j] += lo.x; a1[j] += lo.y; a2[j] += hi.x; a3[j] += hi.y;
                }
            }
        }
    };

    phase(0, cl);                           // low 4 MB sub-table
    __builtin_amdgcn_sched_barrier(0);      // keep phases distinct (no 32-wide fuse)
    phase(HBKT, ch);                        // high 4 MB sub-table

    #pragma unroll
    for (int j = 0; j < 4; ++j) {
        a0[j] += __shfl_xor(a0[j], 16); a0[j] += __shfl_xor(a0[j], 32);
        a1[j] += __shfl_xor(a1[j], 16); a1[j] += __shfl_xor(a1[j], 32);
        a2[j] += __shfl_xor(a2[j], 16); a2[j] += __shfl_xor(a2[j], 32);
        a3[j] += __shfl_xor(a3[j], 16); a3[j] += __shfl_xor(a3[j], 32);
    }

    #pragma unroll
    for (int j = 0; j < 4; ++j) {
        int v = v0 + j;
        ull sx = ((const ull*)xh)[v * 16 + f];   // additive x term (fp16)
        ull st = t2[v * 16 + f];                 // self term t[d]
        unsigned sxl = (unsigned)sx, sxh2 = (unsigned)(sx >> 32);
        unsigned stl = (unsigned)st, sth = (unsigned)(st >> 32);
        float2 xlo = __half22float2(*(const __half2*)&sxl);
        float2 xhi = __half22float2(*(const __half2*)&sxh2);
        float2 slo = __half22float2(*(const __half2*)&stl);
        float2 shi = __half22float2(*(const __half2*)&sth);
        float m = sc * dv[j];
        float r0 = m * (a0[j] + slo.x) + tk * xlo.x;
        float r1 = m * (a1[j] + slo.y) + tk * xlo.y;
        float r2 = m * (a2[j] + shi.x) + tk * xhi.x;
        float r3 = m * (a3[j] + shi.y) + tk * xhi.y;
        if (q == 0) {
            if (k == 9) {
                vfloat4 o = {r0, r1, r2, r3};
                ((vfloat4*)out_f32)[v * 16 + f] = o;
            } else {
                float d2 = dv[j];
                __half2 plo = __floats2half2_rn(d2 * r0, d2 * r1);
                __half2 phi = __floats2half2_rn(d2 * r2, d2 * r3);
                ull o = ((ull)(*(const unsigned*)&phi) << 32)
                      | (*(const unsigned*)&plo);
                ((ull*)tab_out)[v * 16 + f] = o;
            }
        }
    }
}

extern "C" void kernel_launch(void* const* d_in, const int* in_sizes, int n_in,
                              void* d_out, int out_size, void* d_ws, size_t ws_size,
                              hipStream_t stream) {
    const float* x    = (const float*)d_in[0];
    const float* temp = (const float*)d_in[1];
    const int*   ei   = (const int*)d_in[2];
    const int* src = ei;             // edge_index[0]
    const int* dst = ei + N_EDGES;   // edge_index[1]
    float* out = (float*)d_out;

    char* ws = (char*)d_ws;
    int*            counts = (int*)            (ws + 0x000000);   // 512 KB (2 halves)
    int*            rank   = (int*)            (ws + 0x080000);   // 4 MB
    float*          dinv   = (float*)          (ws + 0x080000);   // aliases dead rank
    unsigned short* csr    = (unsigned short*) (ws + 0x480000);   // 8 MB
    __half*         xh     = (__half*)         (ws + 0xC80000);
    __half*         tA     = (__half*)         (ws + 0x1480000);
    __half*         tB     = (__half*)         (ws + 0x1C80000);

    (void)hipMemsetAsync(counts, 0, 2 * N_NODES * sizeof(int), stream);
    (void)hipMemsetAsync(csr, 0, N_NODES * BUCKET * sizeof(unsigned short), stream);

    count_deg<<<N_EDGES / 256, 256, 0, stream>>>(src, dst, counts, rank);
    scatter_src<<<N_EDGES / 256, 256, 0, stream>>>(src, dst, rank, csr);
    // rank is dead now; dinv (aliasing it) is written next, stream-ordered.
    compute_dinv<<<N_NODES / 256, 256, 0, stream>>>(counts, dinv);
    cvt_x<<<(N_NODES * 16) / 256, 256, 0, stream>>>(x, dinv, tA, xh);

    // Horner: p = temp[0]*x; for k=1..9: p = A_hat*p + temp[k]*x (scale fused in hop1)
    // Table invariant t_k = dinv .* p_k; ping-pong tA -> tB -> tA ...
    const int hop_blocks = (N_NODES / 4) * 64 / 256;  // 4 nodes per wave
    const __half* gin = tA;
    for (int k = 1; k <= 9; ++k) {
        __half* gout = (k & 1) ? tB : tA;
        hop_kernel<<<hop_blocks, 256, 0, stream>>>(gin, xh, gout, out, temp,
                                                   counts, csr, dinv, k);
        gin = gout;
    }
}